// Round 13
// baseline (363.717 us; speedup 1.0000x reference)
//
#include <hip/hip_runtime.h>

static constexpr int BLK = 256;
static constexpr int BW_SHIFT = 8;       // bucket = 256 nodes
static constexpr int NBUCK_MAX = 512;    // >= nbuck (391)
static constexpr int CAP = 12288;        // per-bucket capacity (mean ~8192)

typedef __attribute__((ext_vector_type(8))) short bf16x8;
typedef __attribute__((ext_vector_type(4))) float f32x4;

// ---- bf16 helpers ----------------------------------------------------------

__device__ inline float bflo(unsigned u) {
    union { unsigned x; float f; } c; c.x = u << 16; return c.f;
}
__device__ inline float bfhi(unsigned u) {
    union { unsigned x; float f; } c; c.x = u & 0xFFFF0000u; return c.f;
}
__device__ inline unsigned short f2bf(float f) {
    union { float f; unsigned u; } c; c.f = f;
    unsigned u = c.u;
    return (unsigned short)((u + 0x7FFFu + ((u >> 16) & 1u)) >> 16);  // RNE
}
__device__ inline unsigned pack2(float a, float b) {
    return (unsigned)f2bf(a) | ((unsigned)f2bf(b) << 16);
}

// ---- W1 -> W1^T bf16 prep + bcur zeroing (one-shot, tiny) ------------------

__global__ void k_prep_w(const float* __restrict__ W, unsigned short* __restrict__ WT,
                         int* __restrict__ bcur) {
    int t = blockIdx.x * blockDim.x + threadIdx.x;
    if (t < NBUCK_MAX) bcur[t] = 0;
    if (t >= 64 * 128) return;
    int nf = t >> 7, k = t & 127;
    WT[t] = f2bf(W[k * 64 + nf]);
}

// ---- phase A: partition edges into dst-buckets (packed int) ----------------
// payload = src | (dst&255)<<24. 512 blocks x 1024 thr = 2 blocks/CU (100% occ).

__global__ __launch_bounds__(1024) void k_part(
        const int* __restrict__ src, const int* __restrict__ dst,
        int* __restrict__ bcur, int* __restrict__ pairs, int e, int nbuck) {
    __shared__ int hcnt[NBUCK_MAX];
    __shared__ int hbase[NBUCK_MAX];
    const int nt = blockDim.x;
    int nblk = gridDim.x;
    int per = (e + nblk - 1) / nblk;
    int lo = blockIdx.x * per, hi = min(e, lo + per);
    for (int i = threadIdx.x; i < nbuck; i += nt) hcnt[i] = 0;
    __syncthreads();
    for (int i = lo + threadIdx.x; i < hi; i += nt)
        atomicAdd(&hcnt[dst[i] >> BW_SHIFT], 1);
    __syncthreads();
    for (int i = threadIdx.x; i < nbuck; i += nt) {
        int c = hcnt[i];
        hbase[i] = c ? atomicAdd(bcur + i, c) : 0;
        hcnt[i] = 0;
    }
    __syncthreads();
    for (int i = lo + threadIdx.x; i < hi; i += nt) {
        int d = dst[i];
        int b = d >> BW_SHIFT;
        int pos = hbase[b] + atomicAdd(&hcnt[b], 1);
        if (pos < CAP)
            pairs[(size_t)b * CAP + pos] = src[i] | ((d & 255) << 24);
    }
}

// ---- phase B: scan bucket counts -> bucket bases; row_ptr[n] = e -----------

__global__ void k_bktscan(const int* __restrict__ bcur, int* __restrict__ bktbase,
                          int* __restrict__ row_ptr, int nbuck, int n, int e) {
    __shared__ int s[512];
    int v = ((int)threadIdx.x < nbuck) ? bcur[threadIdx.x] : 0;
    s[threadIdx.x] = v;
    __syncthreads();
    for (int off = 1; off < 512; off <<= 1) {
        int t = (threadIdx.x >= (unsigned)off) ? s[threadIdx.x - off] : 0;
        __syncthreads();
        s[threadIdx.x] += t;
        __syncthreads();
    }
    if ((int)threadIdx.x < nbuck)
        bktbase[threadIdx.x] = s[threadIdx.x] - v;   // exclusive
    if (threadIdx.x == 0) row_ptr[n] = e;
}

// ---- phase C: per-bucket counting sort in LDS (1024 threads) ---------------

__global__ __launch_bounds__(1024) void k_bucket_build(
        const int* __restrict__ pairs, const int* __restrict__ bcur,
        const int* __restrict__ bktbase, int* __restrict__ row_ptr,
        float* __restrict__ dinv, int* __restrict__ csr, int n) {
    __shared__ int lcnt[256];
    __shared__ int sexc[256];
    const int b = blockIdx.x;
    const int node0 = b << BW_SHIFT;
    const int nn = min(256, n - node0);
    const int cnt = min(bcur[b], CAP);
    const int base = bktbase[b];
    const int* bp = pairs + (size_t)b * CAP;
    const int tid = threadIdx.x;
    const int nt = blockDim.x;

    if (tid < 256) lcnt[tid] = 0;
    __syncthreads();
    for (int i = tid; i < cnt; i += nt)
        atomicAdd(&lcnt[(unsigned)bp[i] >> 24], 1);
    __syncthreads();
    int c = 0;
    if (tid < 256) {
        c = lcnt[tid];
        sexc[tid] = c;
    }
    __syncthreads();
    for (int off = 1; off < 256; off <<= 1) {
        int t = 0;
        if (tid < 256 && tid >= off) t = sexc[tid - off];
        __syncthreads();
        if (tid < 256) sexc[tid] += t;
        __syncthreads();
    }
    if (tid < nn) {
        int excl = sexc[tid] - c;
        row_ptr[node0 + tid] = base + excl;
        dinv[node0 + tid] = rsqrtf((float)(c + 1));   // +1 self-loop
    }
    __syncthreads();
    if (tid < 256) {
        sexc[tid] -= c;       // exclusive
        lcnt[tid] = 0;
    }
    __syncthreads();
    for (int i = tid; i < cnt; i += nt) {
        int pv = bp[i];
        int ld = (unsigned)pv >> 24;
        int pos = base + sexc[ld] + atomicAdd(&lcnt[ld], 1);
        csr[pos] = pv & 0xFFFFFF;
    }
}

// ---- layer-1 GEMM via bf16 MFMA: G = bf16((X @ W1) * dinv[row]) ------------

__global__ __launch_bounds__(256) void k_gemm1_mfma(
        const float* __restrict__ X, const unsigned short* __restrict__ WT,
        const float* __restrict__ dinv, unsigned short* __restrict__ G, int n) {
    __shared__ unsigned short A_lds[64 * 128];
    __shared__ unsigned short B_lds[64 * 128];
    const int tid = threadIdx.x;
    const int node0 = blockIdx.x * 64;

    // stage B (W^T bf16, 16KB)
    {
        const uint4* srcp = (const uint4*)WT;   // 1024 uint4
#pragma unroll
        for (int v = 0; v < 4; ++v) {
            int idx = tid * 4 + v;
            int r = idx >> 4;
            int bo = (idx & 15) * 16;
            uint4 d = srcp[idx];
            *(uint4*)((char*)B_lds + r * 256 + (bo ^ ((r & 7) << 4))) = d;
        }
    }
    // stage A (x fp32 -> bf16)
    {
        int nd = tid & 63, kq = tid >> 6;
        int row = min(node0 + nd, n - 1);
        const float4* xr = (const float4*)(X + (size_t)row * 128 + kq * 32);
#pragma unroll
        for (int v = 0; v < 4; ++v) {
            float4 f0 = xr[2 * v], f1 = xr[2 * v + 1];
            uint4 d;
            d.x = pack2(f0.x, f0.y); d.y = pack2(f0.z, f0.w);
            d.z = pack2(f1.x, f1.y); d.w = pack2(f1.z, f1.w);
            int bo = kq * 64 + v * 16;
            *(uint4*)((char*)A_lds + nd * 256 + (bo ^ ((nd & 7) << 4))) = d;
        }
    }
    __syncthreads();

    const int lane = tid & 63;
    const int w = tid >> 6;
    const int lm = lane & 15;
    const int lk = lane >> 4;

    f32x4 acc0 = {0, 0, 0, 0}, acc1 = {0, 0, 0, 0};
    f32x4 acc2 = {0, 0, 0, 0}, acc3 = {0, 0, 0, 0};

#pragma unroll
    for (int ks = 0; ks < 4; ++ks) {
        const int kbo = ks * 64 + lk * 16;
        const int ar = w * 16 + lm;
        bf16x8 a = *(bf16x8*)((char*)A_lds + ar * 256 + (kbo ^ ((ar & 7) << 4)));
        {
            const int br = 0 * 16 + lm;
            bf16x8 b = *(bf16x8*)((char*)B_lds + br * 256 + (kbo ^ ((br & 7) << 4)));
            acc0 = __builtin_amdgcn_mfma_f32_16x16x32_bf16(a, b, acc0, 0, 0, 0);
        }
        {
            const int br = 1 * 16 + lm;
            bf16x8 b = *(bf16x8*)((char*)B_lds + br * 256 + (kbo ^ ((br & 7) << 4)));
            acc1 = __builtin_amdgcn_mfma_f32_16x16x32_bf16(a, b, acc1, 0, 0, 0);
        }
        {
            const int br = 2 * 16 + lm;
            bf16x8 b = *(bf16x8*)((char*)B_lds + br * 256 + (kbo ^ ((br & 7) << 4)));
            acc2 = __builtin_amdgcn_mfma_f32_16x16x32_bf16(a, b, acc2, 0, 0, 0);
        }
        {
            const int br = 3 * 16 + lm;
            bf16x8 b = *(bf16x8*)((char*)B_lds + br * 256 + (kbo ^ ((br & 7) << 4)));
            acc3 = __builtin_amdgcn_mfma_f32_16x16x32_bf16(a, b, acc3, 0, 0, 0);
        }
    }

#pragma unroll
    for (int r = 0; r < 4; ++r) {
        int node = node0 + w * 16 + lk * 4 + r;
        if (node < n) {
            float di = dinv[node];
            unsigned short* gp = G + (size_t)node * 64 + lm;
            gp[0]  = f2bf(acc0[r] * di);
            gp[16] = f2bf(acc1[r] * di);
            gp[32] = f2bf(acc2[r] * di);
            gp[48] = f2bf(acc3[r] * di);
        }
    }
}

// ---- tiled fp32 GEMM + dinv scale, bf16 out (layers 2,3) -------------------

template <int K, int F>
__global__ __launch_bounds__(256) void k_gemm_tiled(const float* __restrict__ X,
                                                    const float* __restrict__ W,
                                                    const float* __restrict__ dinv,
                                                    unsigned short* __restrict__ G,
                                                    int n) {
    constexpr int KT = 32;
    constexpr int TF = F / 16;
    static_assert(K % KT == 0, "");
    __shared__ float xs[KT][68];
    __shared__ float wsm[KT * F];
    const int tid = threadIdx.x;
    const int ng = tid & 15;
    const int fg = tid >> 4;
    const int node0 = blockIdx.x * 64;

    float acc[4][TF];
#pragma unroll
    for (int m = 0; m < 4; ++m)
#pragma unroll
        for (int j = 0; j < TF; ++j) acc[m][j] = 0.0f;

    for (int kt = 0; kt < K / KT; ++kt) {
#pragma unroll
        for (int v = 0; v < 2; ++v) {
            int fi = tid + v * 256;
            int nd = fi >> 3, kq = fi & 7;
            int row = min(node0 + nd, n - 1);
            float4 xv = *(const float4*)&X[(size_t)row * K + kt * KT + kq * 4];
            xs[kq * 4 + 0][nd] = xv.x;
            xs[kq * 4 + 1][nd] = xv.y;
            xs[kq * 4 + 2][nd] = xv.z;
            xs[kq * 4 + 3][nd] = xv.w;
        }
        constexpr int WV = KT * F / 4;
        for (int fi = tid; fi < WV; fi += 256)
            ((float4*)wsm)[fi] = ((const float4*)(W + (size_t)kt * KT * F))[fi];
        __syncthreads();

#pragma unroll 8
        for (int kk = 0; kk < KT; ++kk) {
            float4 xv = *(const float4*)&xs[kk][ng * 4];
            float wv[TF];
#pragma unroll
            for (int j = 0; j < TF; ++j) wv[j] = wsm[kk * F + fg * TF + j];
            const float xm[4] = {xv.x, xv.y, xv.z, xv.w};
#pragma unroll
            for (int m = 0; m < 4; ++m)
#pragma unroll
                for (int j = 0; j < TF; ++j) acc[m][j] = fmaf(xm[m], wv[j], acc[m][j]);
        }
        __syncthreads();
    }

#pragma unroll
    for (int m = 0; m < 4; ++m) {
        int node = node0 + ng * 4 + m;
        if (node < n) {
            float di = dinv[node];
            unsigned short* gp = G + (size_t)node * F + fg * TF;
            if constexpr (TF == 2) {
                *(unsigned*)gp = pack2(acc[m][0] * di, acc[m][1] * di);
            } else {
                gp[0] = f2bf(acc[m][0] * di);
            }
        }
    }
}

// ---- gather aggregation (bf16 g): out = relu(dinv*(sum g[src] + g[d]) + b) -
// HEAD=true fuses the 16->4 head GEMM.

template <int F, bool HEAD>
__global__ void k_agg(const int* __restrict__ row_ptr, const int* __restrict__ csr,
                      const uint4* __restrict__ g4, const float* __restrict__ dinv,
                      const float* __restrict__ b, float* __restrict__ out, int n,
                      const float* __restrict__ Wl, const float* __restrict__ blp,
                      float* __restrict__ z_out) {
    constexpr int L = F / 8;
    constexpr int NPB = BLK / L;
    __shared__ float wl_s[68];
    if constexpr (HEAD) {
        if (threadIdx.x < 68)
            wl_s[threadIdx.x] = (threadIdx.x < 64) ? Wl[threadIdx.x]
                                                   : blp[threadIdx.x - 64];
        __syncthreads();
    }
    int node = blockIdx.x * NPB + (int)(threadIdx.x / L);
    int q = threadIdx.x % L;
    if (node >= n) return;
    int i = row_ptr[node], end = row_ptr[node + 1];
    float a[8];
#pragma unroll
    for (int j = 0; j < 8; ++j) a[j] = 0.0f;
    for (; i + 3 < end; i += 4) {
        int s0 = csr[i], s1 = csr[i + 1], s2 = csr[i + 2], s3 = csr[i + 3];
        uint4 v0 = g4[(size_t)s0 * L + q];
        uint4 v1 = g4[(size_t)s1 * L + q];
        uint4 v2 = g4[(size_t)s2 * L + q];
        uint4 v3 = g4[(size_t)s3 * L + q];
        a[0] += (bflo(v0.x) + bflo(v1.x)) + (bflo(v2.x) + bflo(v3.x));
        a[1] += (bfhi(v0.x) + bfhi(v1.x)) + (bfhi(v2.x) + bfhi(v3.x));
        a[2] += (bflo(v0.y) + bflo(v1.y)) + (bflo(v2.y) + bflo(v3.y));
        a[3] += (bfhi(v0.y) + bfhi(v1.y)) + (bfhi(v2.y) + bfhi(v3.y));
        a[4] += (bflo(v0.z) + bflo(v1.z)) + (bflo(v2.z) + bflo(v3.z));
        a[5] += (bfhi(v0.z) + bfhi(v1.z)) + (bfhi(v2.z) + bfhi(v3.z));
        a[6] += (bflo(v0.w) + bflo(v1.w)) + (bflo(v2.w) + bflo(v3.w));
        a[7] += (bfhi(v0.w) + bfhi(v1.w)) + (bfhi(v2.w) + bfhi(v3.w));
    }
    for (; i < end; ++i) {
        uint4 v = g4[(size_t)csr[i] * L + q];
        a[0] += bflo(v.x); a[1] += bfhi(v.x);
        a[2] += bflo(v.y); a[3] += bfhi(v.y);
        a[4] += bflo(v.z); a[5] += bfhi(v.z);
        a[6] += bflo(v.w); a[7] += bfhi(v.w);
    }
    uint4 vs = g4[(size_t)node * L + q];
    a[0] += bflo(vs.x); a[1] += bfhi(vs.x);
    a[2] += bflo(vs.y); a[3] += bfhi(vs.y);
    a[4] += bflo(vs.z); a[5] += bfhi(vs.z);
    a[6] += bflo(vs.w); a[7] += bfhi(vs.w);

    float di = dinv[node];
    float4 b0 = ((const float4*)b)[2 * q];
    float4 b1 = ((const float4*)b)[2 * q + 1];
    float h[8];
    h[0] = fmaxf(fmaf(di, a[0], b0.x), 0.0f);
    h[1] = fmaxf(fmaf(di, a[1], b0.y), 0.0f);
    h[2] = fmaxf(fmaf(di, a[2], b0.z), 0.0f);
    h[3] = fmaxf(fmaf(di, a[3], b0.w), 0.0f);
    h[4] = fmaxf(fmaf(di, a[4], b1.x), 0.0f);
    h[5] = fmaxf(fmaf(di, a[5], b1.y), 0.0f);
    h[6] = fmaxf(fmaf(di, a[6], b1.z), 0.0f);
    h[7] = fmaxf(fmaf(di, a[7], b1.w), 0.0f);
    float4* op = (float4*)out + (size_t)node * (F / 4) + 2 * q;
    op[0] = make_float4(h[0], h[1], h[2], h[3]);
    op[1] = make_float4(h[4], h[5], h[6], h[7]);

    if constexpr (HEAD) {
        float p[4];
#pragma unroll
        for (int j = 0; j < 4; ++j) p[j] = 0.0f;
#pragma unroll
        for (int k = 0; k < 8; ++k) {
            const float hv = h[k];
            const int kr = (q * 8 + k) * 4;
#pragma unroll
            for (int j = 0; j < 4; ++j) p[j] = fmaf(hv, wl_s[kr + j], p[j]);
        }
#pragma unroll
        for (int j = 0; j < 4; ++j) p[j] += __shfl_xor(p[j], 1);
        if (q == 0) {
            float4 zt = make_float4(p[0] + wl_s[64], p[1] + wl_s[65],
                                    p[2] + wl_s[66], p[3] + wl_s[67]);
            ((float4*)z_out)[node] = zt;
        }
    }
}

// ---- launch ----------------------------------------------------------------

extern "C" void kernel_launch(void* const* d_in, const int* in_sizes, int n_in,
                              void* d_out, int out_size, void* d_ws, size_t ws_size,
                              hipStream_t stream) {
    const float* x  = (const float*)d_in[0];
    const int*   ei = (const int*)d_in[1];
    const float* W1 = (const float*)d_in[2];
    const float* b1 = (const float*)d_in[3];
    const float* W2 = (const float*)d_in[4];
    const float* b2 = (const float*)d_in[5];
    const float* W3 = (const float*)d_in[6];
    const float* b3 = (const float*)d_in[7];
    const float* Wl = (const float*)d_in[8];
    const float* bl = (const float*)d_in[9];

    const int n = in_sizes[0] / 128;   // 100000
    const int e = in_sizes[1] / 2;     // 3200000
    const int* src = ei;
    const int* dst = ei + e;

    const int nbuck = (n + (1 << BW_SHIFT) - 1) >> BW_SHIFT;  // 391

    // workspace layout
    char* ws = (char*)d_ws;
    size_t off = 0;
    auto alloc = [&](size_t bytes) {
        char* p = ws + off;
        off += (bytes + 255) & ~(size_t)255;
        return p;
    };
    int*   bcur    = (int*)alloc(NBUCK_MAX * 4);
    int*   bktbase = (int*)alloc(NBUCK_MAX * 4);
    int*   row_ptr = (int*)alloc(((size_t)n + 1) * 4);
    float* dinv    = (float*)alloc((size_t)n * 4);
    unsigned short* w1t = (unsigned short*)alloc(64 * 128 * 2);  // 16 KB
    int*   csr     = (int*)alloc((size_t)e * 4);                // 12.8 MB
    unsigned short* gbuf = (unsigned short*)alloc((size_t)n * 64 * 2);  // 12.8 MB bf16
    float* hbuf    = (float*)alloc((size_t)n * 64 * 4);         // 25.6 MB fp32
    // pairs (19.2 MB) aliases hbuf; fully consumed before the GEMMs run.
    int* pairs = (int*)hbuf;

    float* h_out = (float*)d_out;                   // [n,16]
    float* z_out = (float*)d_out + (size_t)n * 16;  // [n,4]

    // ---- CSR build + W1^T prep (also zeroes bcur) ----
    k_prep_w<<<32, 256, 0, stream>>>(W1, w1t, bcur);
    k_part<<<512, 1024, 0, stream>>>(src, dst, bcur, pairs, e, nbuck);
    k_bktscan<<<1, 512, 0, stream>>>(bcur, bktbase, row_ptr, nbuck, n, e);
    k_bucket_build<<<nbuck, 1024, 0, stream>>>(pairs, bcur, bktbase, row_ptr, dinv, csr, n);

    // ---- layer 1: 128 -> 64 (MFMA) ----
    k_gemm1_mfma<<<(n + 63) / 64, 256, 0, stream>>>(x, w1t, dinv, gbuf, n);
    k_agg<64, false><<<(n + 31) / 32, BLK, 0, stream>>>(row_ptr, csr, (const uint4*)gbuf,
                                                        dinv, b1, hbuf, n, nullptr, nullptr, nullptr);

    // ---- layer 2: 64 -> 32 ----
    k_gemm_tiled<64, 32><<<(n + 63) / 64, 256, 0, stream>>>(hbuf, W2, dinv, gbuf, n);
    k_agg<32, false><<<(n + 63) / 64, BLK, 0, stream>>>(row_ptr, csr, (const uint4*)gbuf,
                                                        dinv, b2, hbuf, n, nullptr, nullptr, nullptr);

    // ---- layer 3: 32 -> 16 (+ fused 16 -> 4 head) ----
    k_gemm_tiled<32, 16><<<(n + 63) / 64, 256, 0, stream>>>(hbuf, W3, dinv, gbuf, n);
    k_agg<16, true><<<(n + 127) / 128, BLK, 0, stream>>>(row_ptr, csr, (const uint4*)gbuf,
                                                         dinv, b3, h_out, n, Wl, bl, z_out);
}